// Round 6
// baseline (7052.075 us; speedup 1.0000x reference)
//
#include <hip/hip_runtime.h>

// ---------------------------------------------------------------------------
// R6: persistent single-kernel encoder with LLC-mediated cross-block handoff.
//  - 256 blocks (8 mt-groups x 32 nt-tiles), all co-resident (1 block/CU).
//  - Shared data (z rows, h A-fragments) moves via AGENT-scope RELAXED atomic
//    loads/stores (sc1 -> device-coherent Infinity Cache; never sits in the
//    non-coherent per-XCD L2s). Weights stay L2-resident (plain loads).
//  - Flags: relaxed spins (NO acquire -> no L2 invalidates, unlike R2).
//    Ordering: __syncthreads drains vmcnt for all waves before the flag add.
//  - Per-mt-group sync only (32 blocks); 8 pipelines destagger.
// Decoder/dense: R4/R5-verified launch-per-step kernels (persist next round).
// ---------------------------------------------------------------------------

typedef __attribute__((ext_vector_type(8)))  short bf16x8;
typedef __attribute__((ext_vector_type(4)))  short short4v;
typedef __attribute__((ext_vector_type(16))) float f32x16;
typedef unsigned long long u64;

#define MFMA(a, b, c) __builtin_amdgcn_mfma_f32_32x32x16_bf16((a), (b), (c), 0, 0, 0)

// ws layout (float offsets). [0, 8388608) = bh/bl bfrag (enc) ALIASED w/ hseq (dec).
#define OFS_ZLL   8388608u    // [256][2048] z, LLC-resident (agent ops only)
#define OFS_CENC  8912896u    // [256][512] c, block-private plain
#define OFS_HENC  9043968u    // [256][512]
#define OFS_HFRAG 9175040u    // hfh64[32768 u64] + hfl64[32768 u64]
#define OFS_XWD   9306112u    // [256][2048]
#define OFS_ZDEC  9830400u    // [2][256][2048]
#define OFS_CDEC  10878976u   // [2][2][256][256]
#define OFS_FLAGS 11141120u   // 4096 ints: zflag[8][256], hflag[8][256]
#define WS_FLOATS 11145216u   // 44.6 MB

__device__ __forceinline__ float frcp(float x) { return __builtin_amdgcn_rcpf(x); }
__device__ __forceinline__ float sigm(float x) { return frcp(1.0f + __expf(-x)); }
__device__ __forceinline__ float tanh1(float x) {
    return 2.0f * frcp(1.0f + __expf(-2.0f * x)) - 1.0f;
}
__device__ __forceinline__ float4 ld4(const float* p) { return *(const float4*)p; }
__device__ __forceinline__ void st4(float* p, float4 v) { *(float4*)p = v; }
__device__ __forceinline__ float4 add4(float4 a, float4 b) {
    return float4{a.x + b.x, a.y + b.y, a.z + b.z, a.w + b.w};
}

__device__ __forceinline__ short f2bf(float f) {
    unsigned u = __float_as_uint(f);
    u = u + 0x7FFFu + ((u >> 16) & 1u);
    return (short)(u >> 16);
}
__device__ __forceinline__ float bf2f(short s) {
    return __uint_as_float(((unsigned)(unsigned short)s) << 16);
}

// ---- LLC (agent-scope, relaxed) access helpers ----
__device__ __forceinline__ float2 ld2f_llc(const float* p) {
    u64 v = __hip_atomic_load((const u64*)p, __ATOMIC_RELAXED, __HIP_MEMORY_SCOPE_AGENT);
    return float2{__uint_as_float((unsigned)v), __uint_as_float((unsigned)(v >> 32))};
}
__device__ __forceinline__ void st1f_llc(float* p, float v) {
    __hip_atomic_store(p, v, __ATOMIC_RELAXED, __HIP_MEMORY_SCOPE_AGENT);
}
__device__ __forceinline__ u64 ld64_llc(const u64* p) {
    return __hip_atomic_load(p, __ATOMIC_RELAXED, __HIP_MEMORY_SCOPE_AGENT);
}
__device__ __forceinline__ void st64_llc(u64* p, u64 v) {
    __hip_atomic_store(p, v, __ATOMIC_RELAXED, __HIP_MEMORY_SCOPE_AGENT);
}
__device__ __forceinline__ void spin_flag(const int* f, int target) {
    while (__hip_atomic_load(f, __ATOMIC_RELAXED, __HIP_MEMORY_SCOPE_AGENT) < target)
        __builtin_amdgcn_s_sleep(4);
}

__global__ __launch_bounds__(256) void init_flags(int* __restrict__ fl) {
    fl[blockIdx.x * 256 + threadIdx.x] = 0;
}

// ---------------------------------------------------------------------------
// bfrag_prep (R4-verified): pack W,U into 32x32x16 B-fragment order.
// lane l holds B[k = ks*16 + (l>>5)*8 + j][col = ct*32 + (l&31)], j=0..7.
// ---------------------------------------------------------------------------
__global__ __launch_bounds__(64) void bfrag_prep(
    const float* __restrict__ W, const float* __restrict__ U,
    short* __restrict__ bh, short* __restrict__ bl)
{
    const int ks = blockIdx.x;          // 0..35
    const int ct = blockIdx.y;          // 0..63
    const int l  = threadIdx.x;
    const int col = ct * 32 + (l & 31);
    const int kbase = ks * 16 + (l >> 5) * 8;
    bf16x8 h8, l8;
    #pragma unroll
    for (int j = 0; j < 8; ++j) {
        const int k = kbase + j;
        const float v = (k < 64) ? W[(size_t)k * 2048 + col]
                                 : U[(size_t)(k - 64) * 2048 + col];
        const short hi = f2bf(v);
        h8[j] = hi;
        l8[j] = f2bf(v - bf2f(hi));
    }
    const size_t off = ((size_t)(ct * 36 + ks) * 64 + l) * 8;
    *(bf16x8*)(bh + off) = h8;
    *(bf16x8*)(bl + off) = l8;
}

// ---------------------------------------------------------------------------
// Persistent encoder. Dynamic LDS: afh[16384]s + afl[16384]s + redv[512]f4.
// ---------------------------------------------------------------------------
__global__ __launch_bounds__(256) void enc_persist(
    const float* __restrict__ x,     // [256][256][64]
    const short* __restrict__ bh, const short* __restrict__ bl,
    const float* __restrict__ bias,  // [2048]
    float* __restrict__ zll,         // [256][2048] LLC
    float* __restrict__ cenc,        // [256][512] private
    float* __restrict__ henc,        // [256][512]
    u64* __restrict__ hfh64, u64* __restrict__ hfl64,  // h A-frags, LLC
    int* __restrict__ fl)
{
    extern __shared__ short lds_s[];
    short* afh = lds_s;                        // 32 KB
    short* afl = lds_s + 16384;                // 32 KB
    float4* redv = (float4*)(lds_s + 32768);   // 8 KB
    u64* afh64 = (u64*)afh;
    u64* afl64 = (u64*)afl;

    const int bid = blockIdx.x;
    const int nt = bid & 31, mt = bid >> 5;
    const int tid = threadIdx.x;
    const int ur = mt * 32 + nt;               // row this block updates
    int* zflag = fl + mt * 256;
    int* hflag = fl + 2048 + mt * 256;

    const int w = tid >> 6, l = tid & 63;
    const int ctl = w & 1, kh = w >> 1;
    const int ct = nt * 2 + ctl;

    for (int t = 0; t < 256; ++t) {
        // ---- wait for h_t, copy A-fragments LLC -> LDS ----
        if (t > 0) {
            if (tid == 0) spin_flag(hflag + t - 1, 32);
            __syncthreads();
            __asm__ volatile("" ::: "memory");
            const u64* gh = hfh64 + (size_t)mt * 4096 + tid * 16;
            const u64* gl = hfl64 + (size_t)mt * 4096 + tid * 16;
            u64 v[16];
            #pragma unroll
            for (int q = 0; q < 16; ++q) v[q] = ld64_llc(gh + q);
            #pragma unroll
            for (int q = 0; q < 16; ++q) afh64[tid * 16 + q] = v[q];
            #pragma unroll
            for (int q = 0; q < 16; ++q) v[q] = ld64_llc(gl + q);
            #pragma unroll
            for (int q = 0; q < 16; ++q) afl64[tid * 16 + q] = v[q];
        }
        __syncthreads();

        // ---- phase A: z_t tile via MFMA (R5-verified datapath) ----
        {
            f32x16 acc;
            #pragma unroll
            for (int i = 0; i < 16; ++i) acc[i] = 0.f;

            if (kh == 0) {
                // x part (4 slabs, A built on the fly)
                const int row = mt * 32 + (l & 31);
                const float* xp = x + ((size_t)row * 256 + t) * 64 + (l >> 5) * 8;
                #pragma unroll
                for (int ks = 0; ks < 4; ++ks) {
                    float xv[8];
                    const float4 xa = ld4(xp + ks * 16);
                    const float4 xb = ld4(xp + ks * 16 + 4);
                    xv[0] = xa.x; xv[1] = xa.y; xv[2] = xa.z; xv[3] = xa.w;
                    xv[4] = xb.x; xv[5] = xb.y; xv[6] = xb.z; xv[7] = xb.w;
                    bf16x8 ah, al;
                    #pragma unroll
                    for (int j = 0; j < 8; ++j) {
                        const short hi = f2bf(xv[j]);
                        ah[j] = hi;
                        al[j] = f2bf(xv[j] - bf2f(hi));
                    }
                    const size_t boff = ((size_t)(ct * 36 + ks) * 64 + l) * 8;
                    const bf16x8 bhv = *(const bf16x8*)(bh + boff);
                    const bf16x8 blv = *(const bf16x8*)(bl + boff);
                    acc = MFMA(ah, bhv, acc);
                    acc = MFMA(ah, blv, acc);
                    acc = MFMA(al, bhv, acc);
                }
                if (t > 0) {
                    for (int ksh = 0; ksh < 14; ++ksh) {
                        const bf16x8 ah = *(const bf16x8*)(afh + (ksh * 64 + l) * 8);
                        const bf16x8 al = *(const bf16x8*)(afl + (ksh * 64 + l) * 8);
                        const size_t boff = ((size_t)(ct * 36 + 4 + ksh) * 64 + l) * 8;
                        const bf16x8 bhv = *(const bf16x8*)(bh + boff);
                        const bf16x8 blv = *(const bf16x8*)(bl + boff);
                        acc = MFMA(ah, bhv, acc);
                        acc = MFMA(ah, blv, acc);
                        acc = MFMA(al, bhv, acc);
                    }
                }
            } else if (t > 0) {
                for (int ksh = 14; ksh < 32; ++ksh) {
                    const bf16x8 ah = *(const bf16x8*)(afh + (ksh * 64 + l) * 8);
                    const bf16x8 al = *(const bf16x8*)(afl + (ksh * 64 + l) * 8);
                    const size_t boff = ((size_t)(ct * 36 + 4 + ksh) * 64 + l) * 8;
                    const bf16x8 bhv = *(const bf16x8*)(bh + boff);
                    const bf16x8 blv = *(const bf16x8*)(bl + boff);
                    acc = MFMA(ah, bhv, acc);
                    acc = MFMA(ah, blv, acc);
                    acc = MFMA(al, bhv, acc);
                }
            }

            if (kh == 1) {
                #pragma unroll
                for (int q = 0; q < 4; ++q)
                    redv[(ctl * 64 + l) * 4 + q] =
                        float4{acc[4 * q], acc[4 * q + 1], acc[4 * q + 2], acc[4 * q + 3]};
            }
            __syncthreads();
            if (kh == 0) {
                #pragma unroll
                for (int q = 0; q < 4; ++q) {
                    const float4 pv = redv[(ctl * 64 + l) * 4 + q];
                    acc[4 * q] += pv.x; acc[4 * q + 1] += pv.y;
                    acc[4 * q + 2] += pv.z; acc[4 * q + 3] += pv.w;
                }
                // C/D layout (verified): col=l&31, row=(i&3)+8*(i>>2)+4*(l>>5)
                const int colg = ct * 32 + (l & 31);
                #pragma unroll
                for (int i = 0; i < 16; ++i) {
                    const int m2 = (i & 3) + 8 * (i >> 2) + 4 * (l >> 5);
                    st1f_llc(zll + (size_t)(mt * 32 + m2) * 2048 + colg, acc[i]);
                }
            }
        }
        __syncthreads();   // drains ALL waves' vmem -> z visible at LLC
        if (tid == 0) {
            __hip_atomic_fetch_add(zflag + t, 1, __ATOMIC_RELAXED, __HIP_MEMORY_SCOPE_AGENT);
            spin_flag(zflag + t, 32);
        }
        __syncthreads();
        __asm__ volatile("" ::: "memory");

        // ---- phase B: update row ur from z_t (wave 0; R4-verified math) ----
        if (tid < 64) {
            const int u = l * 8;
            const float* zr = zll + (size_t)ur * 2048;
            float2 tg[4], ti[4], tf[4], to[4];
            #pragma unroll
            for (int q = 0; q < 4; ++q) tg[q] = ld2f_llc(zr + 1024 + u + q * 2);
            #pragma unroll
            for (int q = 0; q < 4; ++q) ti[q] = ld2f_llc(zr + u + q * 2);
            #pragma unroll
            for (int q = 0; q < 4; ++q) tf[q] = ld2f_llc(zr + 512 + u + q * 2);
            #pragma unroll
            for (int q = 0; q < 4; ++q) to[q] = ld2f_llc(zr + 1536 + u + q * 2);

            float g[8], zi[8], zf[8], zo[8];
            #pragma unroll
            for (int q = 0; q < 4; ++q) {
                g[2 * q] = tg[q].x;  g[2 * q + 1] = tg[q].y;
                zi[2 * q] = ti[q].x; zi[2 * q + 1] = ti[q].y;
                zf[2 * q] = tf[q].x; zf[2 * q + 1] = tf[q].y;
                zo[2 * q] = to[q].x; zo[2 * q + 1] = to[q].y;
            }
            float sg = 0.f;
            #pragma unroll
            for (int j = 0; j < 8; ++j) {
                g[j] = __expf(g[j] + bias[1024 + u + j]);
                sg += g[j];
            }
            #pragma unroll
            for (int m = 1; m < 64; m <<= 1) sg += __shfl_xor(sg, m);
            const float ginv = frcp(sg);

            float ec[8];
            float sc = 0.f;
            #pragma unroll
            for (int j = 0; j < 8; ++j) {
                const float cold = (t > 0) ? cenc[(size_t)ur * 512 + u + j] : 0.f;
                const float cv = sigm(zf[j] + bias[512 + u + j]) * cold
                               + sigm(zi[j] + bias[u + j]) * (g[j] * ginv);
                cenc[(size_t)ur * 512 + u + j] = cv;
                ec[j] = __expf(cv);
                sc += ec[j];
            }
            #pragma unroll
            for (int m = 1; m < 64; m <<= 1) sc += __shfl_xor(sc, m);
            const float cinv = frcp(sc);

            float h[8];
            #pragma unroll
            for (int j = 0; j < 8; ++j)
                h[j] = sigm(zo[j] + bias[1536 + u + j]) * ec[j] * cinv;

            if (t == 255) {
                st4(henc + (size_t)ur * 512 + u,     float4{h[0], h[1], h[2], h[3]});
                st4(henc + (size_t)ur * 512 + u + 4, float4{h[4], h[5], h[6], h[7]});
            }
            // h -> A-fragments (R4-verified mapping): ks=l>>1, lane=(l&1)*32+nt
            union { short4v s; u64 q; } ph0, ph1, pl0, pl1;
            #pragma unroll
            for (int j = 0; j < 4; ++j) {
                const short hi0 = f2bf(h[j]);
                const short hi1 = f2bf(h[j + 4]);
                ph0.s[j] = hi0; pl0.s[j] = f2bf(h[j] - bf2f(hi0));
                ph1.s[j] = hi1; pl1.s[j] = f2bf(h[j + 4] - bf2f(hi1));
            }
            const int ks = l >> 1;
            const int lane = (l & 1) * 32 + nt;
            const size_t j64 = ((size_t)(mt * 32 + ks) * 64 + lane) * 2;
            st64_llc(hfh64 + j64, ph0.q);
            st64_llc(hfh64 + j64 + 1, ph1.q);
            st64_llc(hfl64 + j64, pl0.q);
            st64_llc(hfl64 + j64 + 1, pl1.q);
        }
        if (tid == 0)
            __hip_atomic_fetch_add(hflag + t, 1, __ATOMIC_RELEASE, __HIP_MEMORY_SCOPE_AGENT);
    }
}

// ---------------------------------------------------------------------------
// Decoder (R3/R4-verified): fused step kernel, fp32 VALU.
// ---------------------------------------------------------------------------
__global__ __launch_bounds__(256) void dec_step(
    const float* __restrict__ Uf, const float* __restrict__ Ub,
    const float* __restrict__ xwd, float* __restrict__ zdec,
    float* __restrict__ cdec, float* __restrict__ hseq, int s)
{
    __shared__ float Asd[256 * 33];
    __shared__ float Bsd[2][2048];
    const int bid = blockIdx.x;
    const int nt = bid & 31, mt = bid >> 5;
    const int dir = nt >> 4;
    const int tid = threadIdx.x;

    {
        const int r = tid >> 3, ug = tid & 7;
        const int grow = mt * 32 + r;
        const float* zr = zdec + (size_t)((s - 1) & 1) * 524288 + (size_t)grow * 2048 + dir * 1024;
        const float* xp = xwd + (size_t)grow * 2048 + dir * 1024;
        const float* cp = cdec + (size_t)(s & 1) * 131072 + dir * 65536 + (size_t)grow * 256;
        float*       cn = cdec + (size_t)((s + 1) & 1) * 131072 + dir * 65536 + (size_t)grow * 256;
        const int tt = dir ? (64 - s) : (s - 1);
        #pragma unroll
        for (int m = 0; m < 8; ++m) {
            const int idx = m * 32 + ug * 4;
            float4 zi = ld4(xp + idx);
            float4 zf = ld4(xp + 256 + idx);
            float4 zg = ld4(xp + 512 + idx);
            float4 zo = ld4(xp + 768 + idx);
            float4 cv0{0.f, 0.f, 0.f, 0.f};
            if (s > 1) {
                zi = add4(zi, ld4(zr + idx));
                zf = add4(zf, ld4(zr + 256 + idx));
                zg = add4(zg, ld4(zr + 512 + idx));
                zo = add4(zo, ld4(zr + 768 + idx));
                cv0 = ld4(cp + idx);
            }
            float4 cv, h;
            cv.x = sigm(zf.x) * cv0.x + sigm(zi.x) * tanh1(zg.x);
            cv.y = sigm(zf.y) * cv0.y + sigm(zi.y) * tanh1(zg.y);
            cv.z = sigm(zf.z) * cv0.z + sigm(zi.z) * tanh1(zg.z);
            cv.w = sigm(zf.w) * cv0.w + sigm(zi.w) * tanh1(zg.w);
            st4(cn + idx, cv);
            h.x = sigm(zo.x) * tanh1(cv.x); h.y = sigm(zo.y) * tanh1(cv.y);
            h.z = sigm(zo.z) * tanh1(cv.z); h.w = sigm(zo.w) * tanh1(cv.w);
            Asd[(idx + 0) * 33 + r] = h.x; Asd[(idx + 1) * 33 + r] = h.y;
            Asd[(idx + 2) * 33 + r] = h.z; Asd[(idx + 3) * 33 + r] = h.w;
            if ((nt & 15) == 0)
                st4(hseq + ((size_t)grow * 64 + tt) * 512 + dir * 256 + idx, h);
        }
    }
    __syncthreads();

    if (s < 64) {
        const int tr = tid >> 4, tc = tid & 15;
        const int brow = tid >> 3, bcg = (tid & 7) * 8;
        const int cl = (nt & 15) * 64;
        const float* Ud = dir ? Ub : Uf;
        float4 a0{0.f, 0.f, 0.f, 0.f}, a1{0.f, 0.f, 0.f, 0.f};

        const float* bp0 = Ud + (size_t)brow * 1024 + cl + bcg;
        float4 pb0 = ld4(bp0), pb1 = ld4(bp0 + 4);

        for (int ch = 0; ch < 8; ++ch) {
            float* bs = Bsd[ch & 1];
            st4(bs + brow * 64 + bcg, pb0);
            st4(bs + brow * 64 + bcg + 4, pb1);
            __syncthreads();
            if (ch + 1 < 8) {
                const int k = (ch + 1) * 32 + brow;
                const float* bp = Ud + (size_t)k * 1024 + cl + bcg;
                pb0 = ld4(bp); pb1 = ld4(bp + 4);
            }
            const int kb = ch * 32;
            #pragma unroll
            for (int kk = 0; kk < 32; ++kk) {
                const float av0 = Asd[(kb + kk) * 33 + tr];
                const float av1 = Asd[(kb + kk) * 33 + tr + 16];
                const float4 b = ld4(bs + kk * 64 + tc * 4);
                a0.x = fmaf(av0, b.x, a0.x); a0.y = fmaf(av0, b.y, a0.y);
                a0.z = fmaf(av0, b.z, a0.z); a0.w = fmaf(av0, b.w, a0.w);
                a1.x = fmaf(av1, b.x, a1.x); a1.y = fmaf(av1, b.y, a1.y);
                a1.z = fmaf(av1, b.z, a1.z); a1.w = fmaf(av1, b.w, a1.w);
            }
            __syncthreads();
        }
        float* zo = zdec + (size_t)(s & 1) * 524288 + (size_t)(mt * 32) * 2048 + (size_t)nt * 64;
        st4(zo + tr * 2048 + tc * 4, a0);
        st4(zo + (tr + 16) * 2048 + tc * 4, a1);
    }
}

__global__ __launch_bounds__(128) void dec_proj(
    const float* __restrict__ A, const float* __restrict__ Bf,
    const float* __restrict__ Bb, const float* __restrict__ bf,
    const float* __restrict__ bb, float* __restrict__ xwd)
{
    const int n0 = blockIdx.x * 64;
    const int m0 = blockIdx.y * 32;
    __shared__ __align__(16) float As[16][36];
    __shared__ __align__(16) float Bs[16][68];
    const int tid = threadIdx.x;
    const int am = tid & 31, akq = tid >> 5;
    const int bc4 = tid & 15, bkr = tid >> 4;
    const int cr = tid >> 4, cc = tid & 15;

    float acc[4][4] = {};
    const float* bp = (n0 < 1024) ? Bf : Bb;
    const float* bia = (n0 < 1024) ? bf : bb;
    const int nn = (n0 < 1024) ? n0 : (n0 - 1024);

    for (int kb = 0; kb < 512; kb += 16) {
        {
            const int kg = kb + akq * 4;
            const float4 av = ld4(A + (size_t)(m0 + am) * 512 + kg);
            As[akq * 4 + 0][am] = av.x; As[akq * 4 + 1][am] = av.y;
            As[akq * 4 + 2][am] = av.z; As[akq * 4 + 3][am] = av.w;
        }
        #pragma unroll
        for (int pp = 0; pp < 2; ++pp) {
            const int kg = kb + pp * 8 + bkr;
            *(float4*)&Bs[pp * 8 + bkr][bc4 * 4] = ld4(bp + (size_t)kg * 1024 + nn + bc4 * 4);
        }
        __syncthreads();
        #pragma unroll
        for (int kk = 0; kk < 16; ++kk) {
            const float4 av = *(const float4*)&As[kk][cr * 4];
            const float4 bv = *(const float4*)&Bs[kk][cc * 4];
            const float aa[4] = {av.x, av.y, av.z, av.w};
            const float bbv[4] = {bv.x, bv.y, bv.z, bv.w};
            #pragma unroll
            for (int i = 0; i < 4; ++i)
                #pragma unroll
                for (int j = 0; j < 4; ++j)
                    acc[i][j] = fmaf(aa[i], bbv[j], acc[i][j]);
        }
        __syncthreads();
    }
    #pragma unroll
    for (int i = 0; i < 4; ++i) {
        const int col = nn + cc * 4;
        float4 v = {acc[i][0] + bia[col], acc[i][1] + bia[col + 1],
                    acc[i][2] + bia[col + 2], acc[i][3] + bia[col + 3]};
        st4(xwd + (size_t)(m0 + cr * 4 + i) * 2048 + n0 + cc * 4, v);
    }
}

__global__ __launch_bounds__(256) void dense_kernel(
    const float* __restrict__ hseq, const float* __restrict__ Dk,
    const float* __restrict__ Db, float* __restrict__ out)
{
    __shared__ float dk[8192];
    for (int i = threadIdx.x; i < 8192; i += 256) dk[i] = Dk[i];
    __syncthreads();
    const int f = threadIdx.x & 15;
    const int bt = blockIdx.x * 16 + (threadIdx.x >> 4);
    const float* hs = hseq + (size_t)bt * 512;
    float acc = Db[f];
    #pragma unroll 4
    for (int k = 0; k < 512; k += 4) {
        const float4 hv = ld4(hs + k);
        acc += hv.x * dk[(k + 0) * 16 + f] + hv.y * dk[(k + 1) * 16 + f]
             + hv.z * dk[(k + 2) * 16 + f] + hv.w * dk[(k + 3) * 16 + f];
    }
    out[(size_t)bt * 16 + f] = acc;
}

// ---------------------------------------------------------------------------
extern "C" void kernel_launch(void* const* d_in, const int* in_sizes, int n_in,
                              void* d_out, int out_size, void* d_ws, size_t ws_size,
                              hipStream_t stream)
{
    const float* x    = (const float*)d_in[0];
    const float* encW = (const float*)d_in[1];
    const float* encU = (const float*)d_in[2];
    const float* encB = (const float*)d_in[3];
    const float* dfK  = (const float*)d_in[4];
    const float* dfU  = (const float*)d_in[5];
    const float* dfB  = (const float*)d_in[6];
    const float* dbK  = (const float*)d_in[7];
    const float* dbU  = (const float*)d_in[8];
    const float* dbB  = (const float*)d_in[9];
    const float* dK   = (const float*)d_in[10];
    const float* dB   = (const float*)d_in[11];

    if (ws_size < WS_FLOATS * sizeof(float)) return;

    float* ws    = (float*)d_ws;
    short* bh    = (short*)ws;                   // enc only
    short* bl    = bh + 1179648;
    float* hseq  = ws;                           // alias (decoder phase only)
    float* zll   = ws + OFS_ZLL;
    float* cenc  = ws + OFS_CENC;
    float* henc  = ws + OFS_HENC;
    u64*   hfh64 = (u64*)(ws + OFS_HFRAG);
    u64*   hfl64 = hfh64 + 32768;
    float* xwd   = ws + OFS_XWD;
    float* zdec  = ws + OFS_ZDEC;
    float* cdec  = ws + OFS_CDEC;
    int*   fl    = (int*)(ws + OFS_FLAGS);

    const int ENC_LDS = 73728;  // 32KB afh + 32KB afl + 8KB redv
    hipFuncSetAttribute(reinterpret_cast<const void*>(enc_persist),
                        hipFuncAttributeMaxDynamicSharedMemorySize, ENC_LDS);

    init_flags<<<16, 256, 0, stream>>>(fl);
    bfrag_prep<<<dim3(36, 64), 64, 0, stream>>>(encW, encU, bh, bl);

    enc_persist<<<256, 256, ENC_LDS, stream>>>(x, bh, bl, encB, zll, cenc, henc,
                                               hfh64, hfl64, fl);

    dec_proj<<<dim3(32, 8), 128, 0, stream>>>(henc, dfK, dbK, dfB, dbB, xwd);
    for (int s = 1; s <= 64; ++s)
        dec_step<<<256, 256, 0, stream>>>(dfU, dbU, xwd, zdec, cdec, hseq, s);

    dense_kernel<<<1024, 256, 0, stream>>>(hseq, dK, dB, (float*)d_out);
}